// Round 4
// baseline (283.494 us; speedup 1.0000x reference)
//
#include <hip/hip_runtime.h>
#include <hip/hip_bf16.h>
#include <stdint.h>

// EdgeMessage: message[e,m] = sum_v (edges[e,:]@W[m*64+v,:] + b[m*64+v]) * vertices[e,v]
// R4 restructure (LDS-pipe was the wall at 25% MfmaUtil ceiling):
//  - all-f16 datapath: A[e,k']=V[e,v]*X[e,kk] built with v_pk_mul_f16; W,b in f16.
//  - waves split 2x2: each wave M=64 edges x N=32 cols -> halves LDS B-reads.
//  - W staged via global_load_lds width=16 DMA; XOR swizzle pre-applied in the
//    prep kernel's GLOBAL layout (DMA LDS dest is lane-linear, can't swizzle).
//  - V read from global per (t,v), prefetched one v ahead (keeps LDS at 32KB).

typedef _Float16 f16;
typedef __attribute__((ext_vector_type(2))) _Float16 f16x2;
typedef __attribute__((ext_vector_type(8))) _Float16 f16x8;
typedef __attribute__((ext_vector_type(4))) float f32x4;

#define MSG_D 64
#define VTX_D 64
#define EDG_D 128
#define EPB 128   // edges per block: 2 M-groups x 64

__device__ __forceinline__ void dma16(const void* g, void* l) {
  __builtin_amdgcn_global_load_lds(
      (const __attribute__((address_space(1))) unsigned int*)g,
      (__attribute__((address_space(3))) unsigned int*)l, 16, 0, 0);
}

// ---- prep: W fp32 -> f16, reordered to [v][m][swizzled 16B chunk]; b -> f16 ----
// Wh ushort idx = v*8192 + m*128 + cp*8 + j, cp = (c&8)|((c^(m&7))&7),
// holding W[(m*64+v)*128 + c*8 + j]. 65536 threads, one 16B chunk each.
__global__ void prep_f16(const float* __restrict__ W, const float* __restrict__ b,
                         f16* __restrict__ Wh, f16* __restrict__ bh) {
  int tid = blockIdx.x * 256 + threadIdx.x;
  int c = tid & 15, m = (tid >> 4) & 63, v = tid >> 10;
  const float* src = W + ((size_t)(m * 64 + v) * 128 + c * 8);
  int cp = (c & 8) | ((c ^ (m & 7)) & 7);
  f16* dst = Wh + ((size_t)v * 8192 + m * 128 + cp * 8);
  float4 a = *(const float4*)src;
  float4 d = *(const float4*)(src + 4);
  f16x8 h = {(f16)a.x, (f16)a.y, (f16)a.z, (f16)a.w,
             (f16)d.x, (f16)d.y, (f16)d.z, (f16)d.w};
  *(f16x8*)dst = h;
  if (tid < 4096) bh[tid] = (f16)b[tid];
}

// ---- main fused MFMA kernel ----
__global__ __launch_bounds__(256, 3) void edge_msg_f16(
    const float* __restrict__ Vtx, const float* __restrict__ Xe,
    const f16* __restrict__ Wh, const f16* __restrict__ bh,
    float* __restrict__ out, int E)
{
  __shared__ __align__(16) f16 lds[2][8192];   // 2 x 16KB W chunk [64 m][128 kk]

  const int tid  = threadIdx.x;
  const int lane = tid & 63;
  const int wv   = tid >> 6;
  const int wm   = wv & 1;        // M-half (64 edges)
  const int wn   = wv >> 1;       // N-half (32 cols)
  const int q    = lane >> 4;
  const int ln   = lane & 15;
  const int eoff = blockIdx.x * EPB + wm * 64;

  // ---- preload X as f16 fragments (A[m=ln][k=q*8+j] per t,s) ----
  f16x8 xh[4][4];
  const float* vrow[4];
  #pragma unroll
  for (int t = 0; t < 4; ++t) {
    int e  = eoff + 16 * t + ln;
    int er = e < E ? e : (E - 1);
    const float* xr = Xe + (size_t)er * EDG_D;
    #pragma unroll
    for (int s = 0; s < 4; ++s) {
      float4 a = *(const float4*)(xr + s * 32 + q * 8);
      float4 d = *(const float4*)(xr + s * 32 + q * 8 + 4);
      xh[t][s] = (f16x8){(f16)a.x, (f16)a.y, (f16)a.z, (f16)a.w,
                         (f16)d.x, (f16)d.y, (f16)d.z, (f16)d.w};
    }
    vrow[t] = Vtx + (size_t)er * VTX_D;
  }

  f32x4 acc[4][2];
  #pragma unroll
  for (int t = 0; t < 4; ++t)
    #pragma unroll
    for (int n = 0; n < 2; ++n)
      acc[t][n] = (f32x4){0.f, 0.f, 0.f, 0.f};

  // ---- DMA staging: wave wv covers bytes [wv*4096, +4096) of each 16KB chunk ----
  const char* wsrc = (const char*)Wh + wv * 4096 + lane * 16;
  char* ldst[2] = { (char*)&lds[0][0] + wv * 4096, (char*)&lds[1][0] + wv * 4096 };

  // read byte-offsets within this wave's n-tile (swizzle matches prep)
  int rb[4];
  #pragma unroll
  for (int s = 0; s < 4; ++s) {
    int c  = s * 4 + q;
    int cp = (c & 8) | ((c ^ (ln & 7)) & 7);
    rb[s] = ln * 256 + cp * 16;
  }

  // prologue: DMA v=0 into buf0; preload V scalars
  #pragma unroll
  for (int i = 0; i < 4; ++i) dma16(wsrc + i * 1024, ldst[0] + i * 1024);
  float vv[4], nv[4];
  #pragma unroll
  for (int t = 0; t < 4; ++t) vv[t] = vrow[t][0];
  __syncthreads();

  for (int v = 0; v < 64; ++v) {
    const bool more = (v < 63);
    if (more) {
      const char* g = wsrc + (size_t)(v + 1) * 16384;
      char* l = ldst[(v + 1) & 1];
      #pragma unroll
      for (int i = 0; i < 4; ++i) dma16(g + i * 1024, l + i * 1024);
      #pragma unroll
      for (int t = 0; t < 4; ++t) nv[t] = vrow[t][v + 1];
    }

    f16x2 hh[4];
    #pragma unroll
    for (int t = 0; t < 4; ++t) { f16 h = (f16)vv[t]; hh[t] = (f16x2){h, h}; }

    const char* bufb = (const char*)&lds[v & 1][0] + wn * 8192;
    #pragma unroll
    for (int s = 0; s < 4; ++s) {
      f16x8 bf0 = *(const f16x8*)(bufb + rb[s]);
      f16x8 bf1 = *(const f16x8*)(bufb + rb[s] + 4096);
      #pragma unroll
      for (int t = 0; t < 4; ++t) {
        union { f16x2 h2[4]; f16x8 v8; } af;
        union { f16x8 v8; f16x2 h2[4]; } xs;
        xs.v8 = xh[t][s];
        af.h2[0] = hh[t] * xs.h2[0];
        af.h2[1] = hh[t] * xs.h2[1];
        af.h2[2] = hh[t] * xs.h2[2];
        af.h2[3] = hh[t] * xs.h2[3];
        acc[t][0] = __builtin_amdgcn_mfma_f32_16x16x32_f16(af.v8, bf0, acc[t][0], 0, 0, 0);
        acc[t][1] = __builtin_amdgcn_mfma_f32_16x16x32_f16(af.v8, bf1, acc[t][1], 0, 0, 0);
      }
    }
    __syncthreads();
    #pragma unroll
    for (int t = 0; t < 4; ++t) vv[t] = nv[t];
  }

  // ---- bias: 2 K-steps, A = V[e, s*32+q*8+j], B = bh[col*64 + k] ----
  #pragma unroll
  for (int s = 0; s < 2; ++s) {
    f16x8 av[4];
    #pragma unroll
    for (int t = 0; t < 4; ++t) {
      const float* vr = vrow[t];
      float4 a = *(const float4*)(vr + s * 32 + q * 8);
      float4 d = *(const float4*)(vr + s * 32 + q * 8 + 4);
      av[t] = (f16x8){(f16)a.x, (f16)a.y, (f16)a.z, (f16)a.w,
                      (f16)d.x, (f16)d.y, (f16)d.z, (f16)d.w};
    }
    #pragma unroll
    for (int n = 0; n < 2; ++n) {
      int col = wn * 32 + n * 16 + ln;
      f16x8 bf = *(const f16x8*)(bh + (size_t)col * 64 + s * 32 + q * 8);
      #pragma unroll
      for (int t = 0; t < 4; ++t)
        acc[t][n] = __builtin_amdgcn_mfma_f32_16x16x32_f16(av[t], bf, acc[t][n], 0, 0, 0);
    }
  }

  // ---- store: C layout col=lane&15, row=q*4+r [m89-verified] ----
  #pragma unroll
  for (int t = 0; t < 4; ++t) {
    #pragma unroll
    for (int r = 0; r < 4; ++r) {
      int e = eoff + 16 * t + 4 * q + r;
      if (e < E) {
        float* orow = out + (size_t)e * MSG_D + wn * 32 + ln;
        orow[0]  = acc[t][0][r];
        orow[16] = acc[t][1][r];
      }
    }
  }
}

// ---- fallback (workspace too small): exact fp32, slow but correct ----
__global__ void edge_msg_naive(const float* __restrict__ Vtx, const float* __restrict__ Xe,
                               const float* __restrict__ W, const float* __restrict__ b,
                               float* __restrict__ out, int E) {
  __shared__ float xs[EDG_D];
  __shared__ float vs[VTX_D];
  int e = blockIdx.x;
  int m = threadIdx.x;
  for (int i = m; i < EDG_D; i += 64) xs[i] = Xe[(size_t)e * EDG_D + i];
  for (int i = m; i < VTX_D; i += 64) vs[i] = Vtx[(size_t)e * VTX_D + i];
  __syncthreads();
  float s = 0.f;
  for (int v = 0; v < VTX_D; ++v) {
    const float* wr = W + (size_t)(m * 64 + v) * EDG_D;
    float p = b[m * 64 + v];
    for (int k = 0; k < EDG_D; ++k) p += xs[k] * wr[k];
    s += p * vs[v];
  }
  out[(size_t)e * MSG_D + m] = s;
}

extern "C" void kernel_launch(void* const* d_in, const int* in_sizes, int n_in,
                              void* d_out, int out_size, void* d_ws, size_t ws_size,
                              hipStream_t stream) {
  const float* Vtx = (const float*)d_in[0];   // [E, 64]
  const float* Xe  = (const float*)d_in[1];   // [E, 128]
  const float* W   = (const float*)d_in[2];   // [4096, 128]
  const float* b   = (const float*)d_in[3];   // [4096]
  float* out = (float*)d_out;

  const int E  = in_sizes[0] / VTX_D;
  const int nW = in_sizes[2];                 // 524288
  const int nb = in_sizes[3];                 // 4096
  const size_t need = (size_t)(nW + nb) * sizeof(f16);

  if (ws_size < need || nW != 524288) {
    edge_msg_naive<<<E, 64, 0, stream>>>(Vtx, Xe, W, b, out, E);
    return;
  }

  f16* Wh = (f16*)d_ws;
  f16* bh = Wh + nW;

  prep_f16<<<256, 256, 0, stream>>>(W, b, Wh, bh);

  int blocks = (E + EPB - 1) / EPB;
  edge_msg_f16<<<blocks, 256, 0, stream>>>(Vtx, Xe, Wh, bh, out, E);
}

// Round 5
// 249.178 us; speedup vs baseline: 1.1377x; 1.1377x over previous
//
#include <hip/hip_runtime.h>
#include <hip/hip_bf16.h>
#include <stdint.h>

// EdgeMessage: message[e,m] = sum_v (edges[e,:]@W[m*64+v,:] + b[m*64+v]) * vertices[e,v]
// R5: flatmm-style register-direct W streaming. No LDS, no barriers.
//  - prep_w shuffles W into per-(v,s,n) fragment-stream layout: one coalesced
//    global_load_dwordx4 per wave == one MFMA B-fragment (lane-exact).
//  - wave = 64 edges x 64 cols; per v-step: 16 B-frag loads + 64 MFMA.
//  - compiler emits fine-grained vmcnt for register deps; 2 waves/SIMD
//    cross-cover load latency (m114 MFMA/VALU co-scheduling).
//  - V pre-transposed to Vt[v][e] f16: in-loop V load = 1 cache line.
//  - bias folded as 2 extra K-steps (A = V-frags from original Vtx layout).

typedef _Float16 f16;
typedef __attribute__((ext_vector_type(2))) _Float16 f16x2;
typedef __attribute__((ext_vector_type(8))) _Float16 f16x8;
typedef __attribute__((ext_vector_type(4))) float f32x4;

#define MSG_D 64
#define VTX_D 64
#define EDG_D 128
#define EPB 256   // 4 independent waves x 64 edges

__device__ __forceinline__ f16x8 cvt8(float4 a, float4 d) {
  return (f16x8){(f16)a.x, (f16)a.y, (f16)a.z, (f16)a.w,
                 (f16)d.x, (f16)d.y, (f16)d.z, (f16)d.w};
}

// ---- prep: W -> fragment stream; b -> bias frags ----
// Wh granule tid = (v*16 + s*4 + n)*64 + lane: f16[8] =
//   W[(n*16+ln)*64 + v][s*32 + q*8 + j], lane = q*16+ln.
// Bh granule t2 = (s2*4 + n)*64 + lane: f16[8] = b[(n*16+ln)*64 + s2*32+q*8+j].
__global__ void prep_w(const float* __restrict__ W, const float* __restrict__ b,
                       f16* __restrict__ Wh, f16* __restrict__ Bh) {
  int tid = blockIdx.x * 256 + threadIdx.x;
  if (tid < 65536) {
    int L = tid & 63, n = (tid >> 6) & 3, s = (tid >> 8) & 3, v = tid >> 10;
    int q = L >> 4, ln = L & 15;
    const float* src = W + (size_t)((n * 16 + ln) * 64 + v) * 128 + s * 32 + q * 8;
    float4 a = *(const float4*)src, d = *(const float4*)(src + 4);
    *(f16x8*)(Wh + (size_t)tid * 8) = cvt8(a, d);
  } else if (tid < 66048) {
    int t2 = tid - 65536;
    int L = t2 & 63, n = (t2 >> 6) & 3, s2 = t2 >> 8;
    int q = L >> 4, ln = L & 15;
    const float* src = b + (n * 16 + ln) * 64 + s2 * 32 + q * 8;
    float4 a = *(const float4*)src, d = *(const float4*)(src + 4);
    *(f16x8*)(Bh + (size_t)t2 * 8) = cvt8(a, d);
  }
}

// ---- prep: V [E,64] f32 -> Vt [64,E] f16 (LDS tile transpose) ----
__global__ void prep_vt(const float* __restrict__ V, f16* __restrict__ Vt, int E) {
  __shared__ f16 tile[64][72];
  int e0 = blockIdx.x * 64;
  int t  = threadIdx.x;
  {
    int el = t >> 2, c4 = t & 3;        // read V[e0+el][c4*16 .. +15]
    bool ok = (e0 + el) < E;
    const float* src = V + (size_t)(ok ? e0 + el : 0) * VTX_D + c4 * 16;
    #pragma unroll
    for (int i = 0; i < 4; ++i) {
      float4 a = {0.f, 0.f, 0.f, 0.f};
      if (ok) a = *(const float4*)(src + 4 * i);
      float av[4] = {a.x, a.y, a.z, a.w};
      #pragma unroll
      for (int j = 0; j < 4; ++j) tile[c4 * 16 + i * 4 + j][el] = (f16)av[j];
    }
  }
  __syncthreads();
  int v = t & 63, c = t >> 6;           // write Vt[v][e0 + c*16 .. +15]
  int ebase = e0 + c * 16;
  union { f16 h[16]; f16x8 v8[2]; } o;
  #pragma unroll
  for (int k = 0; k < 16; ++k) o.h[k] = tile[v][c * 16 + k];
  f16* dst = Vt + (size_t)v * E + ebase;
  if (ebase + 16 <= E) {
    *(f16x8*)dst = o.v8[0];
    *(f16x8*)(dst + 8) = o.v8[1];
  } else {
    for (int k = 0; k < 16; ++k)
      if (ebase + k < E) dst[k] = o.h[k];
  }
}

// ---- main kernel: register-direct W stream, no LDS, no barriers ----
template <bool USE_VT>
__global__ __launch_bounds__(256, 2) void edge_msg_flat(
    const float* __restrict__ Vtx, const float* __restrict__ Xe,
    const f16* __restrict__ Wh, const f16* __restrict__ Bh,
    const f16* __restrict__ Vt, float* __restrict__ out, int E)
{
  const int lane = threadIdx.x & 63;
  const int q = lane >> 4, ln = lane & 15;
  const int eoff = blockIdx.x * EPB + (threadIdx.x >> 6) * 64;

  // X fragments f16 (A[m=ln][k=q*8+j] per t,s), rows clamped
  int er[4];
  f16x8 xh[4][4];
  #pragma unroll
  for (int t = 0; t < 4; ++t) {
    int e = eoff + 16 * t + ln;
    er[t] = e < E ? e : E - 1;
    const float* xr = Xe + (size_t)er[t] * EDG_D;
    #pragma unroll
    for (int s = 0; s < 4; ++s) {
      float4 a = *(const float4*)(xr + s * 32 + q * 8);
      float4 d = *(const float4*)(xr + s * 32 + q * 8 + 4);
      xh[t][s] = cvt8(a, d);
    }
  }

  f32x4 acc[4][4];
  #pragma unroll
  for (int t = 0; t < 4; ++t)
    #pragma unroll
    for (int n = 0; n < 4; ++n) acc[t][n] = (f32x4){0.f, 0.f, 0.f, 0.f};

  const f16* wp = Wh + (size_t)lane * 8;

  f16 vc[4];
  #pragma unroll
  for (int t = 0; t < 4; ++t)
    vc[t] = USE_VT ? Vt[er[t]] : (f16)Vtx[(size_t)er[t] * VTX_D];

  #pragma unroll 1
  for (int v = 0; v < 64; ++v) {
    // 16 independent B-frag loads (16 KB, coalesced, L1/L2-resident stream)
    f16x8 wf[16];
    const f16* wrow = wp + (size_t)v * 8192;
    #pragma unroll
    for (int c = 0; c < 16; ++c) wf[c] = *(const f16x8*)(wrow + c * 512);

    // prefetch next-step V scalars
    f16 vn[4];
    int v1 = v + 1 < 64 ? v + 1 : 63;
    #pragma unroll
    for (int t = 0; t < 4; ++t)
      vn[t] = USE_VT ? Vt[(size_t)v1 * E + er[t]]
                     : (f16)Vtx[(size_t)er[t] * VTX_D + v1];

    #pragma unroll
    for (int s = 0; s < 4; ++s) {
      f16x8 af[4];
      #pragma unroll
      for (int t = 0; t < 4; ++t) {
        f16x2 hv = {vc[t], vc[t]};
        union { f16x8 v8; f16x2 h2[4]; } x, r;
        x.v8 = xh[t][s];
        r.h2[0] = hv * x.h2[0];
        r.h2[1] = hv * x.h2[1];
        r.h2[2] = hv * x.h2[2];
        r.h2[3] = hv * x.h2[3];
        af[t] = r.v8;
      }
      #pragma unroll
      for (int n = 0; n < 4; ++n)
        #pragma unroll
        for (int t = 0; t < 4; ++t)
          acc[t][n] = __builtin_amdgcn_mfma_f32_16x16x32_f16(af[t], wf[s * 4 + n], acc[t][n], 0, 0, 0);
    }
    #pragma unroll
    for (int t = 0; t < 4; ++t) vc[t] = vn[t];
  }

  // bias: 2 K-steps, A = V-frags (original layout), B = Bh frags
  #pragma unroll
  for (int s2 = 0; s2 < 2; ++s2) {
    f16x8 av[4];
    #pragma unroll
    for (int t = 0; t < 4; ++t) {
      const float* vr2 = Vtx + (size_t)er[t] * VTX_D + s2 * 32 + q * 8;
      float4 a = *(const float4*)vr2, d = *(const float4*)(vr2 + 4);
      av[t] = cvt8(a, d);
    }
    #pragma unroll
    for (int n = 0; n < 4; ++n) {
      f16x8 bf = *(const f16x8*)(Bh + (size_t)((s2 * 4 + n) * 64 + lane) * 8);
      #pragma unroll
      for (int t = 0; t < 4; ++t)
        acc[t][n] = __builtin_amdgcn_mfma_f32_16x16x32_f16(av[t], bf, acc[t][n], 0, 0, 0);
    }
  }

  // store: C layout col=lane&15 (m), row=q*4+r (edge) [m89-verified]
  #pragma unroll
  for (int t = 0; t < 4; ++t)
    #pragma unroll
    for (int r = 0; r < 4; ++r) {
      int e = eoff + 16 * t + 4 * q + r;
      if (e < E) {
        float* orow = out + (size_t)e * MSG_D;
        #pragma unroll
        for (int n = 0; n < 4; ++n) orow[n * 16 + ln] = acc[t][n][r];
      }
    }
}

// ---- fallback (workspace too small / unexpected shape): exact fp32 ----
__global__ void edge_msg_naive(const float* __restrict__ Vtx, const float* __restrict__ Xe,
                               const float* __restrict__ W, const float* __restrict__ b,
                               float* __restrict__ out, int E) {
  __shared__ float xs[EDG_D];
  __shared__ float vs[VTX_D];
  int e = blockIdx.x;
  int m = threadIdx.x;
  for (int i = m; i < EDG_D; i += 64) xs[i] = Xe[(size_t)e * EDG_D + i];
  for (int i = m; i < VTX_D; i += 64) vs[i] = Vtx[(size_t)e * VTX_D + i];
  __syncthreads();
  float s = 0.f;
  for (int v = 0; v < VTX_D; ++v) {
    const float* wr = W + (size_t)(m * 64 + v) * EDG_D;
    float p = b[m * 64 + v];
    for (int k = 0; k < EDG_D; ++k) p += xs[k] * wr[k];
    s += p * vs[v];
  }
  out[(size_t)e * MSG_D + m] = s;
}

extern "C" void kernel_launch(void* const* d_in, const int* in_sizes, int n_in,
                              void* d_out, int out_size, void* d_ws, size_t ws_size,
                              hipStream_t stream) {
  const float* Vtx = (const float*)d_in[0];   // [E, 64]
  const float* Xe  = (const float*)d_in[1];   // [E, 128]
  const float* W   = (const float*)d_in[2];   // [4096, 128]
  const float* b   = (const float*)d_in[3];   // [4096]
  float* out = (float*)d_out;

  const int E  = in_sizes[0] / VTX_D;
  const int nW = in_sizes[2];                 // 524288
  const int nb = in_sizes[3];                 // 4096

  const size_t needW  = (size_t)(524288 + 4096) * sizeof(f16);   // ~1.01 MB
  const size_t needVt = (size_t)64 * E * sizeof(f16);            // ~12.8 MB

  if (nW != 524288 || nb != 4096 || ws_size < needW) {
    edge_msg_naive<<<E, 64, 0, stream>>>(Vtx, Xe, W, b, out, E);
    return;
  }

  f16* Wh = (f16*)d_ws;
  f16* Bh = Wh + 524288;

  prep_w<<<258, 256, 0, stream>>>(W, b, Wh, Bh);

  int blocks = (E + EPB - 1) / EPB;
  if (ws_size >= needW + needVt && (E & 7) == 0) {
    f16* Vt = Bh + 4096;
    prep_vt<<<(E + 63) / 64, 256, 0, stream>>>(Vtx, Vt, E);
    edge_msg_flat<true><<<blocks, 256, 0, stream>>>(Vtx, Xe, Wh, Bh, Vt, out, E);
  } else {
    edge_msg_flat<false><<<blocks, 256, 0, stream>>>(Vtx, Xe, Wh, Bh, nullptr, out, E);
  }
}

// Round 6
// 247.982 us; speedup vs baseline: 1.1432x; 1.0048x over previous
//
#include <hip/hip_runtime.h>
#include <hip/hip_bf16.h>
#include <stdint.h>

// EdgeMessage: message[e,m] = sum_v (edges[e,:]@W[m*64+v,:] + b[m*64+v]) * vertices[e,v]
// R6: flatmm register-direct W stream + half-step register double-buffer.
//  - wave = 64 edges x 64 cols; per v-step: 16 B-frag loads + 64 MFMA.
//  - wA/wB 8-frag double buffer: every load has a 32-MFMA shadow before use
//    (no WAR serialization, no full-latency exposure per step).
//  - 1-wave (64-thread) blocks, 1563 blocks -> 6.1/CU balance, 2 waves/SIMD.
//  - V from own Vtx row, f32->f16 chunk of 8 per 8 steps, prefetched 1 chunk
//    ahead; v-loop unrolled x8 for static element extraction. No Vt prep.
//  - bias folded as 2 extra K-steps.

typedef _Float16 f16;
typedef __attribute__((ext_vector_type(2))) _Float16 f16x2;
typedef __attribute__((ext_vector_type(8))) _Float16 f16x8;
typedef __attribute__((ext_vector_type(4))) float f32x4;

#define MSG_D 64
#define VTX_D 64
#define EDG_D 128

__device__ __forceinline__ f16x8 cvt8(float4 a, float4 d) {
  return (f16x8){(f16)a.x, (f16)a.y, (f16)a.z, (f16)a.w,
                 (f16)d.x, (f16)d.y, (f16)d.z, (f16)d.w};
}

// ---- prep: W -> fragment stream; b -> bias frags (layout same as R5) ----
// Wh granule tid = (v*16 + c)*64 + lane (c = s*4+n): f16[8] =
//   W[(n*16+ln)*64 + v][s*32 + q*8 + j], lane = q*16+ln.
__global__ void prep_w(const float* __restrict__ W, const float* __restrict__ b,
                       f16* __restrict__ Wh, f16* __restrict__ Bh) {
  int tid = blockIdx.x * 256 + threadIdx.x;
  if (tid < 65536) {
    int L = tid & 63, n = (tid >> 6) & 3, s = (tid >> 8) & 3, v = tid >> 10;
    int q = L >> 4, ln = L & 15;
    const float* src = W + (size_t)((n * 16 + ln) * 64 + v) * 128 + s * 32 + q * 8;
    float4 a = *(const float4*)src, d = *(const float4*)(src + 4);
    *(f16x8*)(Wh + (size_t)tid * 8) = cvt8(a, d);
  } else if (tid < 66048) {
    int t2 = tid - 65536;
    int L = t2 & 63, n = (t2 >> 6) & 3, s2 = t2 >> 8;
    int q = L >> 4, ln = L & 15;
    const float* src = b + (n * 16 + ln) * 64 + s2 * 32 + q * 8;
    float4 a = *(const float4*)src, d = *(const float4*)(src + 4);
    *(f16x8*)(Bh + (size_t)t2 * 8) = cvt8(a, d);
  }
}

// ---- main kernel: 1 wave = 64 edges x 64 cols, no LDS, no barriers ----
__global__ __launch_bounds__(64, 2) void edge_msg_flat(
    const float* __restrict__ Vtx, const float* __restrict__ Xe,
    const f16* __restrict__ Wh, const f16* __restrict__ Bh,
    float* __restrict__ out, int E)
{
  const int lane = threadIdx.x;
  const int q = lane >> 4, ln = lane & 15;
  const int eoff = blockIdx.x * 64;

  // X fragments f16 (A[m=ln][k=q*8+j] per t,s), rows clamped
  int er[4];
  f16x8 xh[4][4];
  #pragma unroll
  for (int t = 0; t < 4; ++t) {
    int e = eoff + 16 * t + ln;
    er[t] = e < E ? e : E - 1;
    const float* xr = Xe + (size_t)er[t] * EDG_D;
    #pragma unroll
    for (int s = 0; s < 4; ++s) {
      float4 a = *(const float4*)(xr + s * 32 + q * 8);
      float4 d = *(const float4*)(xr + s * 32 + q * 8 + 4);
      xh[t][s] = cvt8(a, d);
    }
  }

  f32x4 acc[4][4];
  #pragma unroll
  for (int t = 0; t < 4; ++t)
    #pragma unroll
    for (int n = 0; n < 4; ++n) acc[t][n] = (f32x4){0.f, 0.f, 0.f, 0.f};

  const f16* wp = Wh + (size_t)lane * 8;   // frag c of step v: wp + v*8192 + c*512

  f16x8 wA[8], wB[8];
  #pragma unroll
  for (int c = 0; c < 8; ++c) wA[c] = *(const f16x8*)(wp + c * 512);

  // V chunk 0 (v = 0..7) per t, f32 -> f16x8
  f16x8 vrow[4];
  #pragma unroll
  for (int t = 0; t < 4; ++t) {
    const float* vsrc = Vtx + (size_t)er[t] * VTX_D;
    float4 a = *(const float4*)(vsrc), d = *(const float4*)(vsrc + 4);
    vrow[t] = cvt8(a, d);
  }

  #pragma unroll 1
  for (int c8 = 0; c8 < 8; ++c8) {
    // prefetch next V chunk (consumed 8 steps later)
    f16x8 vnext[4];
    if (c8 < 7) {
      #pragma unroll
      for (int t = 0; t < 4; ++t) {
        const float* vsrc = Vtx + (size_t)er[t] * VTX_D + (c8 + 1) * 8;
        float4 a = *(const float4*)(vsrc), d = *(const float4*)(vsrc + 4);
        vnext[t] = cvt8(a, d);
      }
    }

    #pragma unroll
    for (int j = 0; j < 8; ++j) {
      const int v = c8 * 8 + j;
      const f16* wrow  = wp + (size_t)v * 8192;
      const f16* wrowN = wp + (size_t)(v < 63 ? v + 1 : 63) * 8192;

      // load second half of step v (frags 8..15) -> wB
      #pragma unroll
      for (int c = 0; c < 8; ++c) wB[c] = *(const f16x8*)(wrow + (8 + c) * 512);

      // per-edge V broadcast for this v (static element extract)
      f16x2 hv[4];
      #pragma unroll
      for (int t = 0; t < 4; ++t) { f16 h = vrow[t][j]; hv[t] = (f16x2){h, h}; }

      // compute s = 0,1 from wA
      #pragma unroll
      for (int s = 0; s < 2; ++s) {
        f16x8 af[4];
        #pragma unroll
        for (int t = 0; t < 4; ++t) {
          union { f16x8 v8; f16x2 h2[4]; } x, r;
          x.v8 = xh[t][s];
          r.h2[0] = hv[t] * x.h2[0];
          r.h2[1] = hv[t] * x.h2[1];
          r.h2[2] = hv[t] * x.h2[2];
          r.h2[3] = hv[t] * x.h2[3];
          af[t] = r.v8;
        }
        #pragma unroll
        for (int n = 0; n < 4; ++n)
          #pragma unroll
          for (int t = 0; t < 4; ++t)
            acc[t][n] = __builtin_amdgcn_mfma_f32_16x16x32_f16(af[t], wA[s * 4 + n], acc[t][n], 0, 0, 0);
      }

      // load first half of step v+1 -> wA
      #pragma unroll
      for (int c = 0; c < 8; ++c) wA[c] = *(const f16x8*)(wrowN + c * 512);

      // compute s = 2,3 from wB
      #pragma unroll
      for (int s = 2; s < 4; ++s) {
        f16x8 af[4];
        #pragma unroll
        for (int t = 0; t < 4; ++t) {
          union { f16x8 v8; f16x2 h2[4]; } x, r;
          x.v8 = xh[t][s];
          r.h2[0] = hv[t] * x.h2[0];
          r.h2[1] = hv[t] * x.h2[1];
          r.h2[2] = hv[t] * x.h2[2];
          r.h2[3] = hv[t] * x.h2[3];
          af[t] = r.v8;
        }
        #pragma unroll
        for (int n = 0; n < 4; ++n)
          #pragma unroll
          for (int t = 0; t < 4; ++t)
            acc[t][n] = __builtin_amdgcn_mfma_f32_16x16x32_f16(af[t], wB[(s - 2) * 4 + n], acc[t][n], 0, 0, 0);
      }
    }

    #pragma unroll
    for (int t = 0; t < 4; ++t) vrow[t] = vnext[t];
  }

  // bias: 2 K-steps, A = V-frags (original layout), B = Bh frags
  #pragma unroll
  for (int s2 = 0; s2 < 2; ++s2) {
    f16x8 av[4];
    #pragma unroll
    for (int t = 0; t < 4; ++t) {
      const float* vr2 = Vtx + (size_t)er[t] * VTX_D + s2 * 32 + q * 8;
      float4 a = *(const float4*)vr2, d = *(const float4*)(vr2 + 4);
      av[t] = cvt8(a, d);
    }
    #pragma unroll
    for (int n = 0; n < 4; ++n) {
      f16x8 bf = *(const f16x8*)(Bh + (size_t)((s2 * 4 + n) * 64 + lane) * 8);
      #pragma unroll
      for (int t = 0; t < 4; ++t)
        acc[t][n] = __builtin_amdgcn_mfma_f32_16x16x32_f16(av[t], bf, acc[t][n], 0, 0, 0);
    }
  }

  // store: C layout col=lane&15 (m), row=q*4+r (edge) [m89-verified]
  #pragma unroll
  for (int t = 0; t < 4; ++t)
    #pragma unroll
    for (int r = 0; r < 4; ++r) {
      int e = eoff + 16 * t + 4 * q + r;
      if (e < E) {
        float* orow = out + (size_t)e * MSG_D;
        #pragma unroll
        for (int n = 0; n < 4; ++n) orow[n * 16 + ln] = acc[t][n][r];
      }
    }
}

// ---- fallback (workspace too small / unexpected shape): exact fp32 ----
__global__ void edge_msg_naive(const float* __restrict__ Vtx, const float* __restrict__ Xe,
                               const float* __restrict__ W, const float* __restrict__ b,
                               float* __restrict__ out, int E) {
  __shared__ float xs[EDG_D];
  __shared__ float vs[VTX_D];
  int e = blockIdx.x;
  int m = threadIdx.x;
  for (int i = m; i < EDG_D; i += 64) xs[i] = Xe[(size_t)e * EDG_D + i];
  for (int i = m; i < VTX_D; i += 64) vs[i] = Vtx[(size_t)e * VTX_D + i];
  __syncthreads();
  float s = 0.f;
  for (int v = 0; v < VTX_D; ++v) {
    const float* wr = W + (size_t)(m * 64 + v) * EDG_D;
    float p = b[m * 64 + v];
    for (int k = 0; k < EDG_D; ++k) p += xs[k] * wr[k];
    s += p * vs[v];
  }
  out[(size_t)e * MSG_D + m] = s;
}

extern "C" void kernel_launch(void* const* d_in, const int* in_sizes, int n_in,
                              void* d_out, int out_size, void* d_ws, size_t ws_size,
                              hipStream_t stream) {
  const float* Vtx = (const float*)d_in[0];   // [E, 64]
  const float* Xe  = (const float*)d_in[1];   // [E, 128]
  const float* W   = (const float*)d_in[2];   // [4096, 128]
  const float* b   = (const float*)d_in[3];   // [4096]
  float* out = (float*)d_out;

  const int E  = in_sizes[0] / VTX_D;
  const int nW = in_sizes[2];                 // 524288
  const int nb = in_sizes[3];                 // 4096

  const size_t needW = (size_t)(524288 + 4096) * sizeof(f16);   // ~1.01 MB

  if (nW != 524288 || nb != 4096 || ws_size < needW) {
    edge_msg_naive<<<E, 64, 0, stream>>>(Vtx, Xe, W, b, out, E);
    return;
  }

  f16* Wh = (f16*)d_ws;
  f16* Bh = Wh + 524288;

  prep_w<<<258, 256, 0, stream>>>(W, b, Wh, Bh);

  int blocks = (E + 63) / 64;
  edge_msg_flat<<<blocks, 64, 0, stream>>>(Vtx, Xe, Wh, Bh, out, E);
}